// Round 3
// baseline (200.175 us; speedup 1.0000x reference)
//
#include <hip/hip_runtime.h>
#include <hip/hip_bf16.h>
#include <stdint.h>

#define D_ 1024
#define NSEQ 2048

typedef __attribute__((ext_vector_type(8))) short bf16x8;
typedef __attribute__((ext_vector_type(4))) float f32x4;

static __device__ __forceinline__ unsigned short f2bf(float x) {
    union { __hip_bfloat16 h; unsigned short u; } cv;
    cv.h = __float2bfloat16(x);
    return cv.u;
}

// async global->LDS, 16B per lane. LDS dest = wave-uniform base + lane*16 (HW).
static __device__ __forceinline__ void gload_lds16(const void* g, void* l) {
    __builtin_amdgcn_global_load_lds(
        (const __attribute__((address_space(1))) unsigned int*)(uintptr_t)g,
        (__attribute__((address_space(3))) unsigned int*)(uintptr_t)l, 16, 0, 0);
}

// ---------------- x fp32 -> bf16 ----------------
__global__ __launch_bounds__(256) void cvt_x(const float* __restrict__ x,
                                             __hip_bfloat16* __restrict__ xb) {
    int i = blockIdx.x * 256 + threadIdx.x;
    float4 v = reinterpret_cast<const float4*>(x)[i];
    ushort4 o;
    o.x = f2bf(v.x); o.y = f2bf(v.y); o.z = f2bf(v.z); o.w = f2bf(v.w);
    reinterpret_cast<ushort4*>(xb)[i] = o;
}

// ---------------- W [d][e] fp32 -> Wt [e][d] bf16 (3 weights stacked -> [3072][1024]) ----------------
__global__ __launch_bounds__(256) void wt_kernel(const float* __restrict__ Wq,
                                                 const float* __restrict__ Wk,
                                                 const float* __restrict__ Wv,
                                                 __hip_bfloat16* __restrict__ Wt) {
    const float* W = (blockIdx.z == 0) ? Wq : (blockIdx.z == 1) ? Wk : Wv;
    unsigned short* O = (unsigned short*)(Wt + (size_t)blockIdx.z * D_ * D_);
    __shared__ float tile[32][33];
    int r0 = blockIdx.y * 32, c0 = blockIdx.x * 32;
    int t = threadIdx.x;
    int r = t >> 3, c4 = (t & 7) * 4;
    float4 v = *reinterpret_cast<const float4*>(&W[(size_t)(r0 + r) * D_ + c0 + c4]);
    tile[r][c4 + 0] = v.x; tile[r][c4 + 1] = v.y;
    tile[r][c4 + 2] = v.z; tile[r][c4 + 3] = v.w;
    __syncthreads();
    int er = t >> 3, dc = (t & 7) * 4;
    ushort4 pk;
    pk.x = f2bf(tile[dc + 0][er]); pk.y = f2bf(tile[dc + 1][er]);
    pk.z = f2bf(tile[dc + 2][er]); pk.w = f2bf(tile[dc + 3][er]);
    *reinterpret_cast<ushort4*>(&O[(size_t)(c0 + er) * D_ + r0 + dc]) = pk;
}

// ================= 256x256 8-phase QKV GEMM =================
// C[8192][3072] = Xb[8192][1024] * Wt[3072][1024]^T, epilogue routes Q/K/Vt.
// 512 threads = 8 waves (2m x 4n); per-wave 128x64 out (8x4 frags of 16x16).
// BK=64 as two K-halves of 32. LDS regions (byte offsets, 128 KiB total):
//   reg(buf,op,kk) = buf*65536 + op*32768 + kk*16384, each [256 rows][32 cols] bf16 (64B rows).
// Swizzle: 16B-slot' = slot ^ ((row>>1)&3)  (2-way bank alias = free); realized via
// inverse-swizzled GLOBAL source + swizzled LDS read (gload_lds dest stays linear).
// Schedule: phase (t,q): kk=q>>1, mh=q&1; stage half s=4t+q+5 (delta=5);
// vmcnt(6) at ends of odd phases (3 halves in flight); tail: stage last 3 halves,
// drain vmcnt(0), compute last 2 tiles barrier-free.

struct Frags { bf16x8 a0, a1, a2, a3, b0, b1, b2, b3; };

template <int KK, int MH>
static __device__ __forceinline__ Frags load_frags(const char* bufbase, int aoff, int boff) {
    const char* regA = bufbase + KK * 16384;
    const char* regB = bufbase + 32768 + KK * 16384;
    Frags f;
    f.a0 = *(const bf16x8*)(regA + aoff + (MH * 4 + 0) * 1024);
    f.a1 = *(const bf16x8*)(regA + aoff + (MH * 4 + 1) * 1024);
    f.a2 = *(const bf16x8*)(regA + aoff + (MH * 4 + 2) * 1024);
    f.a3 = *(const bf16x8*)(regA + aoff + (MH * 4 + 3) * 1024);
    f.b0 = *(const bf16x8*)(regB + boff + 0);
    f.b1 = *(const bf16x8*)(regB + boff + 1024);
    f.b2 = *(const bf16x8*)(regB + boff + 2048);
    f.b3 = *(const bf16x8*)(regB + boff + 3072);
    return f;
}

template <int MH>
static __device__ __forceinline__ void apply_mfma(const Frags& f, f32x4 (&acc)[8][4]) {
    acc[MH*4+0][0] = __builtin_amdgcn_mfma_f32_16x16x32_bf16(f.a0, f.b0, acc[MH*4+0][0], 0, 0, 0);
    acc[MH*4+0][1] = __builtin_amdgcn_mfma_f32_16x16x32_bf16(f.a0, f.b1, acc[MH*4+0][1], 0, 0, 0);
    acc[MH*4+0][2] = __builtin_amdgcn_mfma_f32_16x16x32_bf16(f.a0, f.b2, acc[MH*4+0][2], 0, 0, 0);
    acc[MH*4+0][3] = __builtin_amdgcn_mfma_f32_16x16x32_bf16(f.a0, f.b3, acc[MH*4+0][3], 0, 0, 0);
    acc[MH*4+1][0] = __builtin_amdgcn_mfma_f32_16x16x32_bf16(f.a1, f.b0, acc[MH*4+1][0], 0, 0, 0);
    acc[MH*4+1][1] = __builtin_amdgcn_mfma_f32_16x16x32_bf16(f.a1, f.b1, acc[MH*4+1][1], 0, 0, 0);
    acc[MH*4+1][2] = __builtin_amdgcn_mfma_f32_16x16x32_bf16(f.a1, f.b2, acc[MH*4+1][2], 0, 0, 0);
    acc[MH*4+1][3] = __builtin_amdgcn_mfma_f32_16x16x32_bf16(f.a1, f.b3, acc[MH*4+1][3], 0, 0, 0);
    acc[MH*4+2][0] = __builtin_amdgcn_mfma_f32_16x16x32_bf16(f.a2, f.b0, acc[MH*4+2][0], 0, 0, 0);
    acc[MH*4+2][1] = __builtin_amdgcn_mfma_f32_16x16x32_bf16(f.a2, f.b1, acc[MH*4+2][1], 0, 0, 0);
    acc[MH*4+2][2] = __builtin_amdgcn_mfma_f32_16x16x32_bf16(f.a2, f.b2, acc[MH*4+2][2], 0, 0, 0);
    acc[MH*4+2][3] = __builtin_amdgcn_mfma_f32_16x16x32_bf16(f.a2, f.b3, acc[MH*4+2][3], 0, 0, 0);
    acc[MH*4+3][0] = __builtin_amdgcn_mfma_f32_16x16x32_bf16(f.a3, f.b0, acc[MH*4+3][0], 0, 0, 0);
    acc[MH*4+3][1] = __builtin_amdgcn_mfma_f32_16x16x32_bf16(f.a3, f.b1, acc[MH*4+3][1], 0, 0, 0);
    acc[MH*4+3][2] = __builtin_amdgcn_mfma_f32_16x16x32_bf16(f.a3, f.b2, acc[MH*4+3][2], 0, 0, 0);
    acc[MH*4+3][3] = __builtin_amdgcn_mfma_f32_16x16x32_bf16(f.a3, f.b3, acc[MH*4+3][3], 0, 0, 0);
}

__global__ __launch_bounds__(512, 2) void gemm256_qkv(
    const __hip_bfloat16* __restrict__ A,   // Xb [8192][1024]
    const __hip_bfloat16* __restrict__ Bt,  // Wt [3072][1024]
    void* __restrict__ q_out, void* __restrict__ k_out, void* __restrict__ vt_out) {
    constexpr int NT = 16;   // K=1024 / BK=64
    extern __shared__ char lds[];

    const int m0 = blockIdx.x * 256, n0 = blockIdx.y * 256;
    const int tid = threadIdx.x, lane = tid & 63, wid = tid >> 6;
    const int wm = wid >> 2, wn = wid & 3;
    const int lr = lane & 15, lk = lane >> 4;

    const __hip_bfloat16* Apan = A + (size_t)m0 * 1024;
    const __hip_bfloat16* Bpan = Bt + (size_t)n0 * 1024;

    // swizzled LDS read offsets (per-lane constant)
    const int swz = (lk ^ ((lr >> 1) & 3)) << 4;
    const int aoff = (wm * 128 + lr) * 64 + swz;
    const int boff = (wn * 64 + lr) * 64 + swz;

    // stage constants: chunk c = wid*2+j covers rows c*16..+15 of a half (1KB each)
    const int sprow = wid * 32 + (lane >> 2);                      // j=0 source row
    const int sblk = ((lane & 3) ^ ((lane >> 3) & 3)) * 8;         // inverse-swizzled col block

    auto stage = [&](int s) {
        const int Ts = s >> 2, op = s & 1, kks = (s >> 1) & 1;
        char* dst = lds + ((Ts & 1) << 16) + (op << 15) + (kks << 14) + (wid << 11);
        const __hip_bfloat16* g = (op ? Bpan : Apan)
                                  + (size_t)sprow * 1024 + Ts * 64 + kks * 32 + sblk;
        gload_lds16(g, dst);
        gload_lds16(g + (size_t)16 * 1024, dst + 1024);
    };

    f32x4 acc[8][4] = {};

    // prologue: halves s=0..4, then guarantee tile-0 K-lo landed
    stage(0); stage(1); stage(2); stage(3); stage(4);
    asm volatile("s_waitcnt vmcnt(6)" ::: "memory");
    __builtin_amdgcn_s_barrier();

    for (int t = 0; t + 2 < NT; ++t) {
        const char* bb = lds + ((t & 1) << 16);
        const int s0 = 4 * t + 5;
        {   // phase q=0: kk0, mh0
            Frags f = load_frags<0, 0>(bb, aoff, boff);
            stage(s0 + 0);
            __builtin_amdgcn_s_barrier();
            asm volatile("s_waitcnt lgkmcnt(0)" ::: "memory");
            __builtin_amdgcn_sched_barrier(0);
            __builtin_amdgcn_s_setprio(1);
            apply_mfma<0>(f, acc);
            __builtin_amdgcn_s_setprio(0);
            __builtin_amdgcn_s_barrier();
        }
        {   // phase q=1: kk0, mh1  (+vmcnt(6))
            Frags f = load_frags<0, 1>(bb, aoff, boff);
            stage(s0 + 1);
            asm volatile("s_waitcnt vmcnt(6)" ::: "memory");
            __builtin_amdgcn_s_barrier();
            asm volatile("s_waitcnt lgkmcnt(0)" ::: "memory");
            __builtin_amdgcn_sched_barrier(0);
            __builtin_amdgcn_s_setprio(1);
            apply_mfma<1>(f, acc);
            __builtin_amdgcn_s_setprio(0);
            __builtin_amdgcn_s_barrier();
        }
        {   // phase q=2: kk1, mh0
            Frags f = load_frags<1, 0>(bb, aoff, boff);
            stage(s0 + 2);
            __builtin_amdgcn_s_barrier();
            asm volatile("s_waitcnt lgkmcnt(0)" ::: "memory");
            __builtin_amdgcn_sched_barrier(0);
            __builtin_amdgcn_s_setprio(1);
            apply_mfma<0>(f, acc);
            __builtin_amdgcn_s_setprio(0);
            __builtin_amdgcn_s_barrier();
        }
        {   // phase q=3: kk1, mh1  (+vmcnt(6))
            Frags f = load_frags<1, 1>(bb, aoff, boff);
            stage(s0 + 3);
            asm volatile("s_waitcnt vmcnt(6)" ::: "memory");
            __builtin_amdgcn_s_barrier();
            asm volatile("s_waitcnt lgkmcnt(0)" ::: "memory");
            __builtin_amdgcn_sched_barrier(0);
            __builtin_amdgcn_s_setprio(1);
            apply_mfma<1>(f, acc);
            __builtin_amdgcn_s_setprio(0);
            __builtin_amdgcn_s_barrier();
        }
    }

    // tail: stage last 3 halves of tile NT-1, drain, compute last 2 tiles plain
    stage(4 * NT - 3); stage(4 * NT - 2); stage(4 * NT - 1);
    asm volatile("s_waitcnt vmcnt(0)" ::: "memory");
    __builtin_amdgcn_s_barrier();
#pragma unroll
    for (int t = NT - 2; t < NT; ++t) {
        const char* bb = lds + ((t & 1) << 16);
        { Frags f = load_frags<0, 0>(bb, aoff, boff); apply_mfma<0>(f, acc); }
        { Frags f = load_frags<0, 1>(bb, aoff, boff); apply_mfma<1>(f, acc); }
        { Frags f = load_frags<1, 0>(bb, aoff, boff); apply_mfma<0>(f, acc); }
        { Frags f = load_frags<1, 1>(bb, aoff, boff); apply_mfma<1>(f, acc); }
    }

    // epilogue: route Q / K / Vt by output-column segment
#pragma unroll
    for (int m = 0; m < 8; ++m)
#pragma unroll
        for (int n = 0; n < 4; ++n) {
            const int rbase = m0 + wm * 128 + m * 16 + lk * 4;
            const int cbase = n0 + wn * 64 + n * 16 + lr;
            const int seg = cbase >> 10, e = cbase & 1023;
            if (seg < 2) {
                unsigned short* C = (unsigned short*)(seg == 0 ? q_out : k_out);
#pragma unroll
                for (int j = 0; j < 4; ++j)
                    C[(size_t)(rbase + j) * D_ + e] = f2bf(acc[m][n][j]);
            } else {
                unsigned short* Vt = (unsigned short*)vt_out;
                const int b = rbase >> 11, nq = rbase & 2047;
                ushort4 pk;
                pk.x = f2bf(acc[m][n][0]); pk.y = f2bf(acc[m][n][1]);
                pk.z = f2bf(acc[m][n][2]); pk.w = f2bf(acc[m][n][3]);
                *reinterpret_cast<ushort4*>(&Vt[(((size_t)b << 10) + e) * NSEQ + nq]) = pk;
            }
        }
}

// ---------------- NT GEMM, 128x128 tile (scores / PV) ----------------
template <int MODE>
__global__ __launch_bounds__(256) void gemm128(const __hip_bfloat16* __restrict__ A, int lda,
                                               const __hip_bfloat16* __restrict__ Bt, int ldb,
                                               void* __restrict__ o0,
                                               const float* __restrict__ rinv) {
    const int bx = blockIdx.x, by = blockIdx.y, bz = blockIdx.z;
    if (MODE == 2 && by > bx) return;

    const __hip_bfloat16* Ab = A;
    const __hip_bfloat16* Bb = Bt;
    int Kdim = 1024;
    if (MODE == 2) { Ab += (size_t)bz * NSEQ * D_;  Bb += (size_t)bz * NSEQ * D_; }
    if (MODE == 3) { Ab += (size_t)bz * NSEQ * 4096; Bb += (size_t)bz * D_ * NSEQ; Kdim = (bx + 1) * 128; }

    const int m0 = bx * 128, n0 = by * 128;

    __shared__ __hip_bfloat16 As[128 * 32];
    __shared__ __hip_bfloat16 Bs[128 * 32];

    const int tid = threadIdx.x;
    const int lane = tid & 63, wid = tid >> 6;
    const int wm = wid >> 1, wn = wid & 1;
    const int lr = lane & 15, lk = lane >> 4;

    const int srow = wid * 32 + (lane >> 2);
    const int scol = (lane & 3) * 8;
    const __hip_bfloat16* aptr = Ab + (size_t)(m0 + srow) * lda + scol;
    const __hip_bfloat16* bptr = Bb + (size_t)(n0 + srow) * ldb + scol;
    char* AsW = (char*)As + wid * 2048;
    char* BsW = (char*)Bs + wid * 2048;

    f32x4 acc[4][4] = {};

    for (int k0 = 0; k0 < Kdim; k0 += 32) {
        gload_lds16(aptr,                    AsW);
        gload_lds16(aptr + (size_t)16 * lda, AsW + 1024);
        gload_lds16(bptr,                    BsW);
        gload_lds16(bptr + (size_t)16 * ldb, BsW + 1024);
        aptr += 32; bptr += 32;
        __syncthreads();

        bf16x8 af[4], bfr[4];
#pragma unroll
        for (int m = 0; m < 4; ++m)
            af[m] = *reinterpret_cast<const bf16x8*>(&As[(wm * 64 + m * 16 + lr) * 32 + lk * 8]);
#pragma unroll
        for (int n = 0; n < 4; ++n)
            bfr[n] = *reinterpret_cast<const bf16x8*>(&Bs[(wn * 64 + n * 16 + lr) * 32 + lk * 8]);
#pragma unroll
        for (int m = 0; m < 4; ++m)
#pragma unroll
            for (int n = 0; n < 4; ++n)
                acc[m][n] = __builtin_amdgcn_mfma_f32_16x16x32_bf16(af[m], bfr[n], acc[m][n], 0, 0, 0);
        __syncthreads();
    }

#pragma unroll
    for (int m = 0; m < 4; ++m)
#pragma unroll
        for (int n = 0; n < 4; ++n) {
            const int rbase = m0 + wm * 64 + m * 16 + lk * 4;
            const int cbase = n0 + wn * 64 + n * 16 + lr;
            if (MODE == 2) {
                float* S = (float*)o0 + (size_t)bz * NSEQ * NSEQ;
#pragma unroll
                for (int j = 0; j < 4; ++j) {
                    const int qg = rbase + j, kg = cbase;
                    float s = acc[m][n][j] * 0.03125f;   // 1/sqrt(1024)
                    if (kg > qg) s = -1e30f;
                    S[(size_t)qg * NSEQ + kg] = s;
                }
            } else if (MODE == 3) {
                float* O = (float*)o0 + (size_t)bz * NSEQ * D_;
#pragma unroll
                for (int j = 0; j < 4; ++j)
                    O[(size_t)(rbase + j) * D_ + cbase] =
                        acc[m][n][j] * rinv[bz * NSEQ + rbase + j];
            }
        }
}

// ---------------- row softmax (128-col granularity), unnormalized P bf16 in place ----------------
__global__ __launch_bounds__(256) void softmax_rows(float* __restrict__ S,
                                                    float* __restrict__ rinv) {
    int lane = threadIdx.x & 63;
    int row = blockIdx.x * 4 + (threadIdx.x >> 6);
    int q = row & 2047;
    float* srow = S + (size_t)row * NSEQ;
    int L = ((q >> 7) + 1) << 7;

    float mx = -1e30f;
    for (int k = lane * 4; k < L; k += 256) {
        float4 v = *reinterpret_cast<const float4*>(srow + k);
        mx = fmaxf(mx, fmaxf(fmaxf(v.x, v.y), fmaxf(v.z, v.w)));
    }
    for (int off = 32; off > 0; off >>= 1) mx = fmaxf(mx, __shfl_xor(mx, off, 64));

    float sum = 0.f;
    unsigned short* prow = (unsigned short*)srow;
    for (int k = lane * 4; k < L; k += 256) {
        float4 v = *reinterpret_cast<const float4*>(srow + k);
        float e0 = __expf(v.x - mx), e1 = __expf(v.y - mx);
        float e2 = __expf(v.z - mx), e3 = __expf(v.w - mx);
        sum += (e0 + e1) + (e2 + e3);
        ushort4 pk; pk.x = f2bf(e0); pk.y = f2bf(e1); pk.z = f2bf(e2); pk.w = f2bf(e3);
        *reinterpret_cast<ushort4*>(prow + k) = pk;
    }
    for (int off = 32; off > 0; off >>= 1) sum += __shfl_xor(sum, off, 64);
    if (lane == 0) rinv[row] = 1.0f / sum;
}

extern "C" void kernel_launch(void* const* d_in, const int* in_sizes, int n_in,
                              void* d_out, int out_size, void* d_ws, size_t ws_size,
                              hipStream_t stream) {
    const float* x  = (const float*)d_in[0];
    const float* Wq = (const float*)d_in[1];
    const float* Wk = (const float*)d_in[2];
    const float* Wv = (const float*)d_in[3];

    char* ws = (char*)d_ws;
    float*          S    = (float*)(ws);                        // 64 MiB
    __hip_bfloat16* Xb   = (__hip_bfloat16*)(ws + 67108864);    // 16 MiB
    __hip_bfloat16* Q    = (__hip_bfloat16*)(ws + 83886080);    // 16 MiB
    __hip_bfloat16* K    = (__hip_bfloat16*)(ws + 100663296);   // 16 MiB
    __hip_bfloat16* Vt   = (__hip_bfloat16*)(ws + 117440512);   // 16 MiB
    __hip_bfloat16* Wt   = (__hip_bfloat16*)(ws + 134217728);   // 6 MiB
    float*          rinv = (float*)(ws + 140509184);            // 32 KiB

    cvt_x<<<8192, 256, 0, stream>>>(x, Xb);
    wt_kernel<<<dim3(32, 32, 3), 256, 0, stream>>>(Wq, Wk, Wv, Wt);

    // fused QKV: [8192,1024] x [3072,1024]^T, 256^2 8-phase, 128 KiB dynamic LDS
    gemm256_qkv<<<dim3(32, 12), 512, 131072, stream>>>(Xb, Wt, Q, K, Vt);

    // scores
    gemm128<2><<<dim3(16, 16, 4), 256, 0, stream>>>(Q, 1024, K, 1024, S, nullptr);
    softmax_rows<<<2048, 256, 0, stream>>>(S, rinv);
    // PV
    gemm128<3><<<dim3(16, 8, 4), 256, 0, stream>>>((const __hip_bfloat16*)S, 4096, Vt, 2048,
                                                   d_out, rinv);
}